// Round 15
// baseline (107.390 us; speedup 1.0000x reference)
//
#include <hip/hip_runtime.h>
#include <hip/hip_bf16.h>
#include <math.h>

#define T_DIM 512
#define B_DIM 32
#define D_DIM 1024
#define N_DIM 256
#define M_DIM (T_DIM * B_DIM)
#define CHUNK 32
#define NCHUNK (T_DIM / CHUNK)   // 16
#define IBLK 32
#define ST (B_DIM * N_DIM)       // 8192 elems: t-stride in kn/v/q/out
#define BK 32                    // GEMM K-tile
#define NT (D_DIM / BK)          // 32 K-iterations

typedef _Float16 f16;
typedef _Float16 f16x8 __attribute__((ext_vector_type(8)));
typedef _Float16 f16x4 __attribute__((ext_vector_type(4)));
typedef _Float16 f16x2 __attribute__((ext_vector_type(2)));
typedef __fp16   h16x2 __attribute__((ext_vector_type(2)));   // cvt_pkrtz return type
typedef float    f32x4 __attribute__((ext_vector_type(4)));

#define LDK 264   // halves/row for Kh/Qh/Sh (33 quads of 16B - odd -> conflict-free)
#define LDT 40    // halves/row for KhT/W/G/U0T/UT (5 quads - odd)
#define LDV 36    // floats/row for Vl (9 quads - odd)

#define GLOAD_LDS16(g, l)                                         \
  __builtin_amdgcn_global_load_lds(                               \
      (const __attribute__((address_space(1))) void*)(g),         \
      (__attribute__((address_space(3))) void*)(l), 16, 0, 0)

__device__ __forceinline__ f16x8 cvt8(const float4& a, const float4& b) {
  f16x8 h;
  h[0] = (f16)a.x; h[1] = (f16)a.y; h[2] = (f16)a.z; h[3] = (f16)a.w;
  h[4] = (f16)b.x; h[5] = (f16)b.y; h[6] = (f16)b.z; h[7] = (f16)b.w;
  return h;
}

__device__ __forceinline__ f16x8 pk8(const f32x4 a, const f32x4 b) {
  union { f16x8 v; h16x2 p[4]; } u;
  u.p[0] = __builtin_amdgcn_cvt_pkrtz(a[0], a[1]);
  u.p[1] = __builtin_amdgcn_cvt_pkrtz(a[2], a[3]);
  u.p[2] = __builtin_amdgcn_cvt_pkrtz(b[0], b[1]);
  u.p[3] = __builtin_amdgcn_cvt_pkrtz(b[2], b[3]);
  return u.v;
}

// ---------------------------------------------------------------------------
// Kernel 0: convert the three weight matrices fp32 -> f16 once.
// ---------------------------------------------------------------------------
__global__ __launch_bounds__(256) void cvt_w_kernel(
    const float* __restrict__ wk, const float* __restrict__ wv,
    const float* __restrict__ wq, f16* __restrict__ out) {
  const int i = (blockIdx.x * 256 + threadIdx.x) * 8;
  const int m = blockIdx.y;
  const float* src = (m == 0) ? wk : (m == 1) ? wv : wq;
  const float4 f0 = *(const float4*)(src + i);
  const float4 f1 = *(const float4*)(src + i + 4);
  *(f16x8*)(out + (size_t)m * (N_DIM * D_DIM) + i) = cvt8(f0, f1);
}

// ---------------------------------------------------------------------------
// Kernel 1 (round-15): T4 counted-vmcnt pipeline — ROTATION FIXED.
// Round-14's absmax 5170 was deterministic: the `nxt=(t+2)%3` update made
// iter 1 stage tile 3 over un-consumed tile 2. Correct invariant: tile t
// lives in buffer t%3 — compute(k) <- buf k%3, stage(k+2) -> buf (k+2)%3.
// Hazard ledger (re-audited): top of iter k outstanding = {stage(k),
// stage(k+1)} = 12 VMEM ops/wave; vmcnt(6) retires stage(k); each wave
// waits own count THEN s_barrier -> all stage(k) visible. WAR: buf (k+2)%3
// last read in compute(k-1), before every wave's top-of-k barrier; COMPUTE's
// last MFMA consumes the last ds_read so no DS ops pend across the barrier.
// No ds_writes in loop. "memory" asm + sched_barrier(0) pin order (rule 18).
// Peel: k=NT-2 -> vmcnt(6); k=NT-1 -> vmcnt(0). LDS 72 KB -> 2 blocks/CU.
// ---------------------------------------------------------------------------
__global__ __launch_bounds__(256, 2) void proj_gemm_mfma(
    const float* __restrict__ x, const f16* __restrict__ Wh,
    f16* __restrict__ ok, f16* __restrict__ ov, f16* __restrict__ oq) {
  __shared__ __align__(16) float Af[3][128 * BK];  // 3 x 16 KB
  __shared__ __align__(16) f16   Bh[3][128 * BK];  // 3 x 8 KB

  const int tid  = threadIdx.x;
  const int lane = tid & 63;
  const int w    = tid >> 6;
  const int wm   = w >> 1, wn = w & 1;
  const int lr   = lane & 15;
  const int lq   = lane >> 4;

  const int mb  = blockIdx.x * 128;
  const int mat = blockIdx.y >> 1;
  const int nb  = (blockIdx.y & 1) * 128;

  const f16* Wmat = Wh + (size_t)mat * (N_DIM * D_DIM) + (size_t)nb * D_DIM;
  f16*       C    = (mat == 0) ? ok : (mat == 1) ? ov : oq;

  const int ar  = lane >> 3;
  const int acq = (lane & 7) ^ ar;
  const int brr = lane >> 2;
  const int bco = lane & 3;

  f32x4 acc[4][4];
  #pragma unroll
  for (int i = 0; i < 4; ++i)
    #pragma unroll
    for (int j = 0; j < 4; ++j) acc[i][j] = (f32x4){0.f, 0.f, 0.f, 0.f};

  // stage tile t into buffer bi: 4 A-DMA + 2 B-DMA = 6 VMEM ops per wave
#define STAGE(t, bi)                                                         \
  do {                                                                       \
    const int kt_ = (t) * BK;                                                \
    _Pragma("unroll")                                                        \
    for (int j = 0; j < 4; ++j) {                                            \
      const int r = 32 * j + 8 * w + ar;                                     \
      GLOAD_LDS16(x + (size_t)(mb + r) * D_DIM + kt_ + acq * 4,              \
                  &Af[bi][(32 * j + 8 * w) * BK]);                           \
    }                                                                        \
    _Pragma("unroll")                                                        \
    for (int j = 0; j < 2; ++j) {                                            \
      const int r = 64 * j + 16 * w + brr;                                   \
      GLOAD_LDS16(Wmat + (size_t)r * D_DIM + kt_ + bco * 8,                  \
                  &Bh[bi][(64 * j + 16 * w) * BK]);                          \
    }                                                                        \
  } while (0)

#define COMPUTE(bi)                                                          \
  do {                                                                       \
    f16x8 af[4], bf[4];                                                      \
    _Pragma("unroll")                                                        \
    for (int mi = 0; mi < 4; ++mi) {                                         \
      const int row = 64 * wm + 16 * mi + lr;                                \
      const int q0  = (2 * lq)     ^ (row & 7);                              \
      const int q1  = (2 * lq + 1) ^ (row & 7);                              \
      const f32x4 a0 = *(const f32x4*)&Af[bi][row * BK + q0 * 4];            \
      const f32x4 a1 = *(const f32x4*)&Af[bi][row * BK + q1 * 4];            \
      af[mi] = pk8(a0, a1);                                                  \
    }                                                                        \
    _Pragma("unroll")                                                        \
    for (int nj = 0; nj < 4; ++nj) {                                         \
      const int row = 64 * wn + 16 * nj + lr;                                \
      bf[nj] = *(const f16x8*)&Bh[bi][row * BK + lq * 8];                    \
    }                                                                        \
    _Pragma("unroll")                                                        \
    for (int mi = 0; mi < 4; ++mi)                                           \
      _Pragma("unroll")                                                      \
      for (int nj = 0; nj < 4; ++nj)                                         \
        acc[mi][nj] = __builtin_amdgcn_mfma_f32_16x16x32_f16(                \
            af[mi], bf[nj], acc[mi][nj], 0, 0, 0);                           \
  } while (0)

  // prologue: 2-deep prefetch (tile t -> buffer t%3)
  STAGE(0, 0);
  STAGE(1, 1);

  for (int k = 0; k < NT - 2; ++k) {
    const int cb = k % 3;
    const int nb3 = (k + 2) % 3;
    asm volatile("s_waitcnt vmcnt(6)" ::: "memory");   // stage(k) complete
    __builtin_amdgcn_s_barrier();                      // all waves' stage(k) visible
    __builtin_amdgcn_sched_barrier(0);
    COMPUTE(cb);
    STAGE(k + 2, nb3);
  }
  // k = NT-2: stage(NT-1) is the newest 6 -> vmcnt(6) completes stage(NT-2)
  asm volatile("s_waitcnt vmcnt(6)" ::: "memory");
  __builtin_amdgcn_s_barrier();
  __builtin_amdgcn_sched_barrier(0);
  COMPUTE((NT - 2) % 3);
  // k = NT-1: nothing behind it -> full drain
  asm volatile("s_waitcnt vmcnt(0)" ::: "memory");
  __builtin_amdgcn_s_barrier();
  __builtin_amdgcn_sched_barrier(0);
  COMPUTE((NT - 1) % 3);

#undef STAGE
#undef COMPUTE

  // epilogue: C/D layout col = lane&15, row = (lane>>4)*4 + r ; store f16
  #pragma unroll
  for (int mi = 0; mi < 4; ++mi)
    #pragma unroll
    for (int nj = 0; nj < 4; ++nj)
      #pragma unroll
      for (int r = 0; r < 4; ++r) {
        const int rg = mb + 64 * wm + 16 * mi + 4 * lq + r;
        const int cg = nb + 64 * wn + 16 * nj + lr;
        C[(size_t)rg * N_DIM + cg] = (f16)acc[mi][nj][r];
      }
}

// ---------------------------------------------------------------------------
// Kernel 2: k-row L2 normalize in place, f16 storage (fp32 math).
// ---------------------------------------------------------------------------
__global__ __launch_bounds__(256) void knorm_kernel(f16* __restrict__ k) {
  const int w    = threadIdx.x >> 6;
  const int lane = threadIdx.x & 63;
  const int row  = blockIdx.x * 4 + w;
  f16* p = k + (size_t)row * N_DIM + lane * 4;
  f16x4 h = *reinterpret_cast<const f16x4*>(p);
  const float x0 = (float)h[0], x1 = (float)h[1], x2 = (float)h[2], x3 = (float)h[3];
  float ss = x0 * x0 + x1 * x1 + x2 * x2 + x3 * x3;
  #pragma unroll
  for (int m = 1; m < 64; m <<= 1) ss += __shfl_xor(ss, m, 64);
  const float inv = 1.0f / (sqrtf(ss) + 1e-6f);
  h[0] = (f16)(x0 * inv); h[1] = (f16)(x1 * inv);
  h[2] = (f16)(x2 * inv); h[3] = (f16)(x3 * inv);
  *reinterpret_cast<f16x4*>(p) = h;
}

// ---------------------------------------------------------------------------
// Kernel 3: per-(batch,chunk) WY factors + coalesced K^T emission (frozen).
// ---------------------------------------------------------------------------
__global__ __launch_bounds__(256, 2) void precompute_wg(
    const f16* __restrict__ kn, const f16* __restrict__ q,
    f16* __restrict__ Wg, f16* __restrict__ Gg, f16* __restrict__ KTg) {
  __shared__ __align__(16) f16 Kh[32 * LDK];
  __shared__ __align__(16) f16 Qh[32 * LDK];
  __shared__ float Al[32 * 33];

  const int tid  = threadIdx.x;
  const int lane = tid & 63;
  const int w    = tid >> 6;
  const int lr   = lane & 15;
  const int lq   = lane >> 4;
  const int tm   = w >> 1, tn = w & 1;
  const int b    = blockIdx.x >> 4;
  const int c    = blockIdx.x & 15;
  const int t0g  = c * CHUNK;

  {
    const int t = tid >> 3, cg = tid & 7;
    const f16* ks = kn + (size_t)(t0g + t) * ST + b * N_DIM + cg * 32;
    const f16* qs = q  + (size_t)(t0g + t) * ST + b * N_DIM + cg * 32;
    #pragma unroll
    for (int m = 0; m < 4; ++m) {
      *(f16x8*)&Kh[t * LDK + cg * 32 + 8 * m] = ((const f16x8*)ks)[m];
      *(f16x8*)&Qh[t * LDK + cg * 32 + 8 * m] = ((const f16x8*)qs)[m];
    }
  }
  __syncthreads();

  {
    f16* kt_dst = KTg + ((size_t)blockIdx.x * N_DIM + tid) * CHUNK;
    #pragma unroll
    for (int t8 = 0; t8 < 4; ++t8) {
      f16x8 h;
      #pragma unroll
      for (int e = 0; e < 8; ++e) h[e] = Kh[(8 * t8 + e) * LDK + tid];
      *(f16x8*)(kt_dst + 8 * t8) = h;
    }
  }

  f32x4 Aa = {0.f, 0.f, 0.f, 0.f}, Ga = {0.f, 0.f, 0.f, 0.f};
  #pragma unroll
  for (int kk = 0; kk < 8; ++kk) {
    f16x8 ka = *(const f16x8*)&Kh[(16 * tm + lr) * LDK + 32 * kk + 8 * lq];
    f16x8 qa = *(const f16x8*)&Qh[(16 * tm + lr) * LDK + 32 * kk + 8 * lq];
    f16x8 kb = *(const f16x8*)&Kh[(16 * tn + lr) * LDK + 32 * kk + 8 * lq];
    Aa = __builtin_amdgcn_mfma_f32_16x16x32_f16(ka, kb, Aa, 0, 0, 0);
    Ga = __builtin_amdgcn_mfma_f32_16x16x32_f16(qa, kb, Ga, 0, 0, 0);
  }
  {
    const int s = 16 * tn + lr;
    f16* gdst = Gg + (size_t)blockIdx.x * 1280;
    #pragma unroll
    for (int r = 0; r < 4; ++r) {
      const int t = 16 * tm + 4 * lq + r;
      Al[t * 33 + s] = (s < t) ? Aa[r] : 0.f;
      gdst[t * LDT + s] = (f16)((s <= t) ? Ga[r] : 0.f);
    }
  }
  __syncthreads();

  if (tid < 32) {
    float wv[32];
    f16* wdst = Wg + (size_t)blockIdx.x * 1280;
    #pragma unroll
    for (int t = 0; t < 32; ++t) {
      float s0 = 0.f, s1 = 0.f, s2 = 0.f, s3 = 0.f;
      #pragma unroll
      for (int s = 0; s < 32; ++s) {
        if (s >= t) break;
        const float a = Al[t * 33 + s];
        if ((s & 3) == 0) s0 = fmaf(a, wv[s], s0);
        else if ((s & 3) == 1) s1 = fmaf(a, wv[s], s1);
        else if ((s & 3) == 2) s2 = fmaf(a, wv[s], s2);
        else s3 = fmaf(a, wv[s], s3);
      }
      wv[t] = ((t == tid) ? 1.f : 0.f) - ((s0 + s1) + (s2 + s3));
    }
    #pragma unroll
    for (int t = 0; t < 32; ++t) wdst[t * LDT + tid] = (f16)wv[t];
  }
}

// ---------------------------------------------------------------------------
// Kernel 4: scan, 8 waves + wave-role split (frozen at round-13 config).
// ---------------------------------------------------------------------------
__global__ __launch_bounds__(512, 1) void scan_chunked(
    const f16* __restrict__ kn, const f16* __restrict__ v,
    const f16* __restrict__ q, const float* __restrict__ S0,
    const f16* __restrict__ Wg, const f16* __restrict__ Gg,
    const f16* __restrict__ KTg, float* __restrict__ out) {
  __shared__ __align__(16) f16 Kh[32 * LDK];
  __shared__ __align__(16) f16 Qh[32 * LDK];
  __shared__ __align__(16) f16 Sh[32 * LDK];
  __shared__ __align__(16) f16 KhT[256 * LDT];
  __shared__ __align__(16) f16 Wl[32 * LDT];
  __shared__ __align__(16) f16 Gl[32 * LDT];
  __shared__ __align__(16) f16 U0T[32 * LDT];
  __shared__ __align__(16) f16 UT[32 * LDT];
  __shared__ __align__(16) float Vl[32 * LDV];

  const int tid  = threadIdx.x;
  const int lane = tid & 63;
  const int w    = tid >> 6;          // 0..7
  const int lr   = lane & 15;
  const int lq   = lane >> 4;
  const int role = w >> 2;            // 0 = P-wave, 1 = Oq-wave
  const int w4   = w & 3;
  const int tm   = w4 >> 1, tn = w4 & 1;
  const int b    = blockIdx.x & 31;
  const int i0   = (blockIdx.x >> 5) * IBLK;

  f32x4 acc[2][2];
  const float* S0b = S0 + (size_t)b * N_DIM * N_DIM + (size_t)i0 * N_DIM;
  #pragma unroll
  for (int ti = 0; ti < 2; ++ti)
    #pragma unroll
    for (int jt = 0; jt < 2; ++jt)
      #pragma unroll
      for (int r = 0; r < 4; ++r) {
        const int i = 16 * ti + 4 * lq + r;
        const int j = 32 * w + 16 * jt + lr;
        acc[ti][jt][r] = S0b[(size_t)i * N_DIM + j];
      }
  {
    const int i = tid >> 4, cg = tid & 15;
    const float* ss = S0b + (size_t)i * N_DIM + cg * 16;
    #pragma unroll
    for (int m = 0; m < 2; ++m) {
      float4 f0 = *(const float4*)(ss + 8 * m);
      float4 f1 = *(const float4*)(ss + 8 * m + 4);
      *(f16x8*)&Sh[i * LDK + cg * 16 + 8 * m] = cvt8(f0, f1);
    }
  }
  __syncthreads();

  for (int c = 0; c < NCHUNK; ++c) {
    const int t0g = c * CHUNK;
    {
      const int t = tid >> 4, cg = tid & 15;
      const f16* ks = kn + (size_t)(t0g + t) * ST + b * N_DIM + cg * 16;
      const f16* qs = q  + (size_t)(t0g + t) * ST + b * N_DIM + cg * 16;
      #pragma unroll
      for (int m = 0; m < 2; ++m) {
        *(f16x8*)&Kh[t * LDK + cg * 16 + 8 * m] = ((const f16x8*)ks)[m];
        *(f16x8*)&Qh[t * LDK + cg * 16 + 8 * m] = ((const f16x8*)qs)[m];
      }
      const int c2 = (tid & 15) * 2;
      const f16x2 vf = *(const f16x2*)(v + (size_t)(t0g + t) * ST + b * N_DIM + i0 + c2);
      *(float2*)&Vl[t * LDV + c2] = make_float2((float)vf[0], (float)vf[1]);
    }
    {
      const int row = tid >> 1, m0 = (tid & 1) * 2;
      const f16* src = KTg + ((size_t)(b * NCHUNK + c) * N_DIM + row) * CHUNK;
      #pragma unroll
      for (int m = 0; m < 2; ++m)
        *(f16x8*)&KhT[row * LDT + 8 * (m0 + m)] = ((const f16x8*)src)[m0 + m];
    }
    if (tid < 160) {
      ((f16x8*)Wl)[tid] = ((const f16x8*)(Wg + (size_t)(b * NCHUNK + c) * 1280))[tid];
    } else if (tid < 320) {
      ((f16x8*)Gl)[tid - 160] = ((const f16x8*)(Gg + (size_t)(b * NCHUNK + c) * 1280))[tid - 160];
    }
    __syncthreads();

    f32x4 Oq = {0.f, 0.f, 0.f, 0.f};
    if (role == 0) {
      f32x4 Pacc = {0.f, 0.f, 0.f, 0.f};
      #pragma unroll
      for (int kk = 0; kk < 8; ++kk) {
        f16x8 ka = *(const f16x8*)&Kh[(16 * tm + lr) * LDK + 32 * kk + 8 * lq];
        f16x8 sb = *(const f16x8*)&Sh[(16 * tn + lr) * LDK + 32 * kk + 8 * lq];
        Pacc = __builtin_amdgcn_mfma_f32_16x16x32_f16(ka, sb, Pacc, 0, 0, 0);
      }
      const int i = 16 * tn + lr;
      const int t0 = 16 * tm + 4 * lq;
      f16x4 u0;
      #pragma unroll
      for (int r = 0; r < 4; ++r) u0[r] = (f16)(Vl[(t0 + r) * LDV + i] - Pacc[r]);
      *(f16x4*)&U0T[i * LDT + t0] = u0;
    } else {
      #pragma unroll
      for (int kk = 0; kk < 8; ++kk) {
        f16x8 qa = *(const f16x8*)&Qh[(16 * tm + lr) * LDK + 32 * kk + 8 * lq];
        f16x8 sb = *(const f16x8*)&Sh[(16 * tn + lr) * LDK + 32 * kk + 8 * lq];
        Oq = __builtin_amdgcn_mfma_f32_16x16x32_f16(qa, sb, Oq, 0, 0, 0);
      }
    }
    __syncthreads();

    if (role == 0) {
      f16x8 wa = *(const f16x8*)&Wl[(16 * tm + lr) * LDT + 8 * lq];
      f16x8 ub = *(const f16x8*)&U0T[(16 * tn + lr) * LDT + 8 * lq];
      f32x4 z = {0.f, 0.f, 0.f, 0.f};
      f32x4 Ud = __builtin_amdgcn_mfma_f32_16x16x32_f16(wa, ub, z, 0, 0, 0);
      const int i = 16 * tn + lr;
      const int t0 = 16 * tm + 4 * lq;
      f16x4 uh;
      #pragma unroll
      for (int r = 0; r < 4; ++r) uh[r] = (f16)Ud[r];
      *(f16x4*)&UT[i * LDT + t0] = uh;
    }
    __syncthreads();

    if (role == 1) {
      f16x8 ga = *(const f16x8*)&Gl[(16 * tm + lr) * LDT + 8 * lq];
      f16x8 ub = *(const f16x8*)&UT[(16 * tn + lr) * LDT + 8 * lq];
      f32x4 O = __builtin_amdgcn_mfma_f32_16x16x32_f16(ga, ub, Oq, 0, 0, 0);
      const int i = 16 * tn + lr;
      const int tt0 = 16 * tm + 4 * lq;
      #pragma unroll
      for (int r = 0; r < 4; ++r) {
        const float sq = O[r];
        const float sig = 1.0f / (1.0f + __expf(-sq));
        out[(size_t)(t0g + tt0 + r) * ST + b * N_DIM + i0 + i] = sq * sq * sig;
      }
    }
    #pragma unroll
    for (int ti = 0; ti < 2; ++ti) {
      f16x8 ua = *(const f16x8*)&UT[(16 * ti + lr) * LDT + 8 * lq];
      #pragma unroll
      for (int jt = 0; jt < 2; ++jt) {
        f16x8 kb = *(const f16x8*)&KhT[(32 * w + 16 * jt + lr) * LDT + 8 * lq];
        acc[ti][jt] = __builtin_amdgcn_mfma_f32_16x16x32_f16(ua, kb, acc[ti][jt], 0, 0, 0);
      }
    }
    #pragma unroll
    for (int ti = 0; ti < 2; ++ti)
      #pragma unroll
      for (int jt = 0; jt < 2; ++jt)
        #pragma unroll
        for (int r = 0; r < 4; ++r)
          Sh[(16 * ti + 4 * lq + r) * LDK + 32 * w + 16 * jt + lr] = (f16)acc[ti][jt][r];
    __syncthreads();
  }
}

// ---------------------------------------------------------------------------
extern "C" void kernel_launch(void* const* d_in, const int* in_sizes, int n_in,
                              void* d_out, int out_size, void* d_ws, size_t ws_size,
                              hipStream_t stream) {
  (void)in_sizes; (void)n_in; (void)out_size; (void)ws_size;
  const float* x  = (const float*)d_in[0];
  const float* S0 = (const float*)d_in[1];
  const float* Wk = (const float*)d_in[2];
  const float* Wv = (const float*)d_in[3];
  const float* Wq = (const float*)d_in[4];
  float* outp = (float*)d_out;

  // ws: kn | v | q (f16, 3 x 8.4MB) | Wg | Gg | KTg (8.4MB) | Wh  ~= 37.8MB
  f16* kn  = (f16*)d_ws;
  f16* vv  = kn + (size_t)M_DIM * N_DIM;
  f16* qq  = vv + (size_t)M_DIM * N_DIM;
  f16* Wg  = qq + (size_t)M_DIM * N_DIM;
  f16* Gg  = Wg + (size_t)B_DIM * NCHUNK * 1280;
  f16* KTg = Gg + (size_t)B_DIM * NCHUNK * 1280;
  f16* Wh  = KTg + (size_t)B_DIM * NCHUNK * N_DIM * CHUNK;

  dim3 gw(N_DIM * D_DIM / 8 / 256, 3);
  cvt_w_kernel<<<gw, 256, 0, stream>>>(Wk, Wv, Wq, Wh);
  dim3 gg(M_DIM / 128, 6);
  proj_gemm_mfma<<<gg, 256, 0, stream>>>(x, Wh, kn, vv, qq);
  knorm_kernel<<<M_DIM / 4, 256, 0, stream>>>(kn);
  precompute_wg<<<B_DIM * NCHUNK, 256, 0, stream>>>(kn, qq, Wg, Gg, KTg);
  scan_chunked<<<B_DIM * (N_DIM / IBLK), 512, 0, stream>>>(kn, vv, qq, S0, Wg, Gg, KTg, outp);
}

// Round 16
// 92.111 us; speedup vs baseline: 1.1659x; 1.1659x over previous
//
#include <hip/hip_runtime.h>
#include <hip/hip_bf16.h>
#include <math.h>

#define T_DIM 512
#define B_DIM 32
#define D_DIM 1024
#define N_DIM 256
#define M_DIM (T_DIM * B_DIM)
#define CHUNK 32
#define NCHUNK (T_DIM / CHUNK)   // 16
#define IBLK 32
#define ST (B_DIM * N_DIM)       // 8192 elems: t-stride in kn/v/q/out
#define BK 32                    // GEMM K-tile (frozen round-12 config)

typedef _Float16 f16;
typedef _Float16 f16x8 __attribute__((ext_vector_type(8)));
typedef _Float16 f16x4 __attribute__((ext_vector_type(4)));
typedef _Float16 f16x2 __attribute__((ext_vector_type(2)));
typedef __fp16   h16x2 __attribute__((ext_vector_type(2)));   // cvt_pkrtz return type
typedef float    f32x4 __attribute__((ext_vector_type(4)));

#define LDK 264   // halves/row for Kh/Qh/Sh (33 quads of 16B - odd -> conflict-free)
#define LDT 40    // halves/row for KhT/W/G/U0T/UT (5 quads - odd)
#define LDV 36    // floats/row for Vl (9 quads - odd)

#define GLOAD_LDS16(g, l)                                         \
  __builtin_amdgcn_global_load_lds(                               \
      (const __attribute__((address_space(1))) void*)(g),         \
      (__attribute__((address_space(3))) void*)(l), 16, 0, 0)

__device__ __forceinline__ f16x8 cvt8(const float4& a, const float4& b) {
  f16x8 h;
  h[0] = (f16)a.x; h[1] = (f16)a.y; h[2] = (f16)a.z; h[3] = (f16)a.w;
  h[4] = (f16)b.x; h[5] = (f16)b.y; h[6] = (f16)b.z; h[7] = (f16)b.w;
  return h;
}

__device__ __forceinline__ f16x8 pk8(const f32x4 a, const f32x4 b) {
  union { f16x8 v; h16x2 p[4]; } u;
  u.p[0] = __builtin_amdgcn_cvt_pkrtz(a[0], a[1]);
  u.p[1] = __builtin_amdgcn_cvt_pkrtz(a[2], a[3]);
  u.p[2] = __builtin_amdgcn_cvt_pkrtz(b[0], b[1]);
  u.p[3] = __builtin_amdgcn_cvt_pkrtz(b[2], b[3]);
  return u.v;
}

// ---------------------------------------------------------------------------
// Kernel 0: convert the three weight matrices fp32 -> f16 once.
// ---------------------------------------------------------------------------
__global__ __launch_bounds__(256) void cvt_w_kernel(
    const float* __restrict__ wk, const float* __restrict__ wv,
    const float* __restrict__ wq, f16* __restrict__ out) {
  const int i = (blockIdx.x * 256 + threadIdx.x) * 8;
  const int m = blockIdx.y;
  const float* src = (m == 0) ? wk : (m == 1) ? wv : wq;
  const float4 f0 = *(const float4*)(src + i);
  const float4 f1 = *(const float4*)(src + i + 4);
  *(f16x8*)(out + (size_t)m * (N_DIM * D_DIM) + i) = cvt8(f0, f1);
}

// ---------------------------------------------------------------------------
// Kernel 1: GEMM — REVERTED to the round-12 config (53.6 us, replay-proven).
// r15's counted-vmcnt (72KB/2-blk) lost to this (48KB/3-blk): cross-block
// overlap beats within-block pipelining here. 4 structure experiments all
// land at the same ~53 us plateau -> frozen for good.
// ---------------------------------------------------------------------------
__global__ __launch_bounds__(256, 3) void proj_gemm_mfma(
    const float* __restrict__ x, const f16* __restrict__ Wh,
    f16* __restrict__ ok, f16* __restrict__ ov, f16* __restrict__ oq) {
  __shared__ __align__(16) float Af[2][128 * BK];  // 2 x 16 KB
  __shared__ __align__(16) f16   Bh[2][128 * BK];  // 2 x 8 KB

  const int tid  = threadIdx.x;
  const int lane = tid & 63;
  const int w    = tid >> 6;
  const int wm   = w >> 1, wn = w & 1;
  const int lr   = lane & 15;
  const int lq   = lane >> 4;

  const int mb  = blockIdx.x * 128;
  const int mat = blockIdx.y >> 1;
  const int nb  = (blockIdx.y & 1) * 128;

  const f16* Wmat = Wh + (size_t)mat * (N_DIM * D_DIM) + (size_t)nb * D_DIM;
  f16*       C    = (mat == 0) ? ok : (mat == 1) ? ov : oq;

  const int ar  = lane >> 3;
  const int acq = (lane & 7) ^ ar;
  const int brr = lane >> 2;
  const int bco = lane & 3;

  f32x4 acc[4][4];
  #pragma unroll
  for (int i = 0; i < 4; ++i)
    #pragma unroll
    for (int j = 0; j < 4; ++j) acc[i][j] = (f32x4){0.f, 0.f, 0.f, 0.f};

  #pragma unroll
  for (int j = 0; j < 4; ++j) {
    const int r = 32 * j + 8 * w + ar;
    GLOAD_LDS16(x + (size_t)(mb + r) * D_DIM + acq * 4, &Af[0][(32 * j + 8 * w) * BK]);
  }
  #pragma unroll
  for (int j = 0; j < 2; ++j) {
    const int r = 64 * j + 16 * w + brr;
    GLOAD_LDS16(Wmat + (size_t)r * D_DIM + bco * 8, &Bh[0][(64 * j + 16 * w) * BK]);
  }
  __syncthreads();

  int cur = 0;
  for (int kt = 0; kt < D_DIM; kt += BK) {
    if (kt + BK < D_DIM) {
      #pragma unroll
      for (int j = 0; j < 4; ++j) {
        const int r = 32 * j + 8 * w + ar;
        GLOAD_LDS16(x + (size_t)(mb + r) * D_DIM + kt + BK + acq * 4,
                    &Af[cur ^ 1][(32 * j + 8 * w) * BK]);
      }
      #pragma unroll
      for (int j = 0; j < 2; ++j) {
        const int r = 64 * j + 16 * w + brr;
        GLOAD_LDS16(Wmat + (size_t)r * D_DIM + kt + BK + bco * 8,
                    &Bh[cur ^ 1][(64 * j + 16 * w) * BK]);
      }
    }
    {
      f16x8 af[4], bf[4];
      #pragma unroll
      for (int mi = 0; mi < 4; ++mi) {
        const int row = 64 * wm + 16 * mi + lr;
        const int q0  = (2 * lq)     ^ (row & 7);
        const int q1  = (2 * lq + 1) ^ (row & 7);
        const f32x4 a0 = *(const f32x4*)&Af[cur][row * BK + q0 * 4];
        const f32x4 a1 = *(const f32x4*)&Af[cur][row * BK + q1 * 4];
        af[mi] = pk8(a0, a1);
      }
      #pragma unroll
      for (int nj = 0; nj < 4; ++nj) {
        const int row = 64 * wn + 16 * nj + lr;
        bf[nj] = *(const f16x8*)&Bh[cur][row * BK + lq * 8];
      }
      #pragma unroll
      for (int mi = 0; mi < 4; ++mi)
        #pragma unroll
        for (int nj = 0; nj < 4; ++nj)
          acc[mi][nj] = __builtin_amdgcn_mfma_f32_16x16x32_f16(af[mi], bf[nj], acc[mi][nj], 0, 0, 0);
    }
    __syncthreads();
    cur ^= 1;
  }

  #pragma unroll
  for (int mi = 0; mi < 4; ++mi)
    #pragma unroll
    for (int nj = 0; nj < 4; ++nj)
      #pragma unroll
      for (int r = 0; r < 4; ++r) {
        const int rg = mb + 64 * wm + 16 * mi + 4 * lq + r;
        const int cg = nb + 64 * wn + 16 * nj + lr;
        C[(size_t)rg * N_DIM + cg] = (f16)acc[mi][nj][r];
      }
}

// ---------------------------------------------------------------------------
// Kernel 2: k-row L2 normalize in place, f16 storage (fp32 math).
// ---------------------------------------------------------------------------
__global__ __launch_bounds__(256) void knorm_kernel(f16* __restrict__ k) {
  const int w    = threadIdx.x >> 6;
  const int lane = threadIdx.x & 63;
  const int row  = blockIdx.x * 4 + w;
  f16* p = k + (size_t)row * N_DIM + lane * 4;
  f16x4 h = *reinterpret_cast<const f16x4*>(p);
  const float x0 = (float)h[0], x1 = (float)h[1], x2 = (float)h[2], x3 = (float)h[3];
  float ss = x0 * x0 + x1 * x1 + x2 * x2 + x3 * x3;
  #pragma unroll
  for (int m = 1; m < 64; m <<= 1) ss += __shfl_xor(ss, m, 64);
  const float inv = 1.0f / (sqrtf(ss) + 1e-6f);
  h[0] = (f16)(x0 * inv); h[1] = (f16)(x1 * inv);
  h[2] = (f16)(x2 * inv); h[3] = (f16)(x3 * inv);
  *reinterpret_cast<f16x4*>(p) = h;
}

// ---------------------------------------------------------------------------
// Kernel 3: per-(batch,chunk) WY factors + coalesced K^T emission (frozen).
// ---------------------------------------------------------------------------
__global__ __launch_bounds__(256, 2) void precompute_wg(
    const f16* __restrict__ kn, const f16* __restrict__ q,
    f16* __restrict__ Wg, f16* __restrict__ Gg, f16* __restrict__ KTg) {
  __shared__ __align__(16) f16 Kh[32 * LDK];
  __shared__ __align__(16) f16 Qh[32 * LDK];
  __shared__ float Al[32 * 33];

  const int tid  = threadIdx.x;
  const int lane = tid & 63;
  const int w    = tid >> 6;
  const int lr   = lane & 15;
  const int lq   = lane >> 4;
  const int tm   = w >> 1, tn = w & 1;
  const int b    = blockIdx.x >> 4;
  const int c    = blockIdx.x & 15;
  const int t0g  = c * CHUNK;

  {
    const int t = tid >> 3, cg = tid & 7;
    const f16* ks = kn + (size_t)(t0g + t) * ST + b * N_DIM + cg * 32;
    const f16* qs = q  + (size_t)(t0g + t) * ST + b * N_DIM + cg * 32;
    #pragma unroll
    for (int m = 0; m < 4; ++m) {
      *(f16x8*)&Kh[t * LDK + cg * 32 + 8 * m] = ((const f16x8*)ks)[m];
      *(f16x8*)&Qh[t * LDK + cg * 32 + 8 * m] = ((const f16x8*)qs)[m];
    }
  }
  __syncthreads();

  {
    f16* kt_dst = KTg + ((size_t)blockIdx.x * N_DIM + tid) * CHUNK;
    #pragma unroll
    for (int t8 = 0; t8 < 4; ++t8) {
      f16x8 h;
      #pragma unroll
      for (int e = 0; e < 8; ++e) h[e] = Kh[(8 * t8 + e) * LDK + tid];
      *(f16x8*)(kt_dst + 8 * t8) = h;
    }
  }

  f32x4 Aa = {0.f, 0.f, 0.f, 0.f}, Ga = {0.f, 0.f, 0.f, 0.f};
  #pragma unroll
  for (int kk = 0; kk < 8; ++kk) {
    f16x8 ka = *(const f16x8*)&Kh[(16 * tm + lr) * LDK + 32 * kk + 8 * lq];
    f16x8 qa = *(const f16x8*)&Qh[(16 * tm + lr) * LDK + 32 * kk + 8 * lq];
    f16x8 kb = *(const f16x8*)&Kh[(16 * tn + lr) * LDK + 32 * kk + 8 * lq];
    Aa = __builtin_amdgcn_mfma_f32_16x16x32_f16(ka, kb, Aa, 0, 0, 0);
    Ga = __builtin_amdgcn_mfma_f32_16x16x32_f16(qa, kb, Ga, 0, 0, 0);
  }
  {
    const int s = 16 * tn + lr;
    f16* gdst = Gg + (size_t)blockIdx.x * 1280;
    #pragma unroll
    for (int r = 0; r < 4; ++r) {
      const int t = 16 * tm + 4 * lq + r;
      Al[t * 33 + s] = (s < t) ? Aa[r] : 0.f;
      gdst[t * LDT + s] = (f16)((s <= t) ? Ga[r] : 0.f);
    }
  }
  __syncthreads();

  if (tid < 32) {
    float wv[32];
    f16* wdst = Wg + (size_t)blockIdx.x * 1280;
    #pragma unroll
    for (int t = 0; t < 32; ++t) {
      float s0 = 0.f, s1 = 0.f, s2 = 0.f, s3 = 0.f;
      #pragma unroll
      for (int s = 0; s < 32; ++s) {
        if (s >= t) break;
        const float a = Al[t * 33 + s];
        if ((s & 3) == 0) s0 = fmaf(a, wv[s], s0);
        else if ((s & 3) == 1) s1 = fmaf(a, wv[s], s1);
        else if ((s & 3) == 2) s2 = fmaf(a, wv[s], s2);
        else s3 = fmaf(a, wv[s], s3);
      }
      wv[t] = ((t == tid) ? 1.f : 0.f) - ((s0 + s1) + (s2 + s3));
    }
    #pragma unroll
    for (int t = 0; t < 32; ++t) wdst[t * LDT + tid] = (f16)wv[t];
  }
}

// ---------------------------------------------------------------------------
// Kernel 4 (round-16): scan with T14 issue-early / write-late staging.
// Round-13 base (8 waves, wave-role split). Change: chunk c+1's global
// loads issued into REGISTERS at the top of chunk c (they land during the
// 4 compute phases); each LDS buffer is ds_written right after the barrier
// that retires its last reader: Kh/Qh/Vl after B1 (phase-1 readers), Wl
// after B2 (phase-2), Gl/KhT after B3 (phase-3/4). Every write->read pair
// has >=1 uniform __syncthreads between them; no DMA or counted waits.
// Barriers 4 -> 3 per chunk.
// ---------------------------------------------------------------------------
__global__ __launch_bounds__(512, 1) void scan_chunked(
    const f16* __restrict__ kn, const f16* __restrict__ v,
    const f16* __restrict__ q, const float* __restrict__ S0,
    const f16* __restrict__ Wg, const f16* __restrict__ Gg,
    const f16* __restrict__ KTg, float* __restrict__ out) {
  __shared__ __align__(16) f16 Kh[32 * LDK];
  __shared__ __align__(16) f16 Qh[32 * LDK];
  __shared__ __align__(16) f16 Sh[32 * LDK];
  __shared__ __align__(16) f16 KhT[256 * LDT];
  __shared__ __align__(16) f16 Wl[32 * LDT];
  __shared__ __align__(16) f16 Gl[32 * LDT];
  __shared__ __align__(16) f16 U0T[32 * LDT];
  __shared__ __align__(16) f16 UT[32 * LDT];
  __shared__ __align__(16) float Vl[32 * LDV];

  const int tid  = threadIdx.x;
  const int lane = tid & 63;
  const int w    = tid >> 6;          // 0..7
  const int lr   = lane & 15;
  const int lq   = lane >> 4;
  const int role = w >> 2;            // 0 = P-wave, 1 = Oq-wave
  const int w4   = w & 3;
  const int tm   = w4 >> 1, tn = w4 & 1;
  const int b    = blockIdx.x & 31;
  const int i0   = (blockIdx.x >> 5) * IBLK;

  // staging geometry (shared by prologue + in-loop writes)
  const int st_t  = tid >> 4, st_cg = tid & 15;     // K/Q rows
  const int st_c2 = (tid & 15) * 2;                 // V cols
  const int kt_row = tid >> 1, kt_m0 = (tid & 1) * 2;

  f32x4 acc[2][2];
  const float* S0b = S0 + (size_t)b * N_DIM * N_DIM + (size_t)i0 * N_DIM;
  #pragma unroll
  for (int ti = 0; ti < 2; ++ti)
    #pragma unroll
    for (int jt = 0; jt < 2; ++jt)
      #pragma unroll
      for (int r = 0; r < 4; ++r) {
        const int i = 16 * ti + 4 * lq + r;
        const int j = 32 * w + 16 * jt + lr;
        acc[ti][jt][r] = S0b[(size_t)i * N_DIM + j];
      }
  {
    const float* ss = S0b + (size_t)st_t * N_DIM + st_cg * 16;
    #pragma unroll
    for (int m = 0; m < 2; ++m) {
      float4 f0 = *(const float4*)(ss + 8 * m);
      float4 f1 = *(const float4*)(ss + 8 * m + 4);
      *(f16x8*)&Sh[st_t * LDK + st_cg * 16 + 8 * m] = cvt8(f0, f1);
    }
  }
  // ---- prologue: stage chunk 0 fully
  {
    const f16* ks = kn + (size_t)st_t * ST + b * N_DIM + st_cg * 16;
    const f16* qs = q  + (size_t)st_t * ST + b * N_DIM + st_cg * 16;
    #pragma unroll
    for (int m = 0; m < 2; ++m) {
      *(f16x8*)&Kh[st_t * LDK + st_cg * 16 + 8 * m] = ((const f16x8*)ks)[m];
      *(f16x8*)&Qh[st_t * LDK + st_cg * 16 + 8 * m] = ((const f16x8*)qs)[m];
    }
    const f16x2 vf = *(const f16x2*)(v + (size_t)st_t * ST + b * N_DIM + i0 + st_c2);
    *(float2*)&Vl[st_t * LDV + st_c2] = make_float2((float)vf[0], (float)vf[1]);
    const f16* src = KTg + ((size_t)(b * NCHUNK) * N_DIM + kt_row) * CHUNK;
    #pragma unroll
    for (int m = 0; m < 2; ++m)
      *(f16x8*)&KhT[kt_row * LDT + 8 * (kt_m0 + m)] = ((const f16x8*)src)[kt_m0 + m];
    if (tid < 160) {
      ((f16x8*)Wl)[tid] = ((const f16x8*)(Wg + (size_t)(b * NCHUNK) * 1280))[tid];
    } else if (tid < 320) {
      ((f16x8*)Gl)[tid - 160] = ((const f16x8*)(Gg + (size_t)(b * NCHUNK) * 1280))[tid - 160];
    }
  }
  __syncthreads();

  for (int c = 0; c < NCHUNK; ++c) {
    const int t0g = c * CHUNK;
    const bool more = (c + 1) < NCHUNK;

    // ---- issue chunk c+1's global loads (in flight through phases 1-4)
    f16x8 nk[2], nq[2], nkt[2], nwg;
    f16x2 nv;
    if (more) {
      const f16* ks = kn + (size_t)(t0g + CHUNK + st_t) * ST + b * N_DIM + st_cg * 16;
      const f16* qs = q  + (size_t)(t0g + CHUNK + st_t) * ST + b * N_DIM + st_cg * 16;
      #pragma unroll
      for (int m = 0; m < 2; ++m) { nk[m] = ((const f16x8*)ks)[m]; nq[m] = ((const f16x8*)qs)[m]; }
      nv = *(const f16x2*)(v + (size_t)(t0g + CHUNK + st_t) * ST + b * N_DIM + i0 + st_c2);
      const f16* src = KTg + ((size_t)(b * NCHUNK + c + 1) * N_DIM + kt_row) * CHUNK;
      #pragma unroll
      for (int m = 0; m < 2; ++m) nkt[m] = ((const f16x8*)src)[kt_m0 + m];
      if (tid < 160)      nwg = ((const f16x8*)(Wg + (size_t)(b * NCHUNK + c + 1) * 1280))[tid];
      else if (tid < 320) nwg = ((const f16x8*)(Gg + (size_t)(b * NCHUNK + c + 1) * 1280))[tid - 160];
    }

    // ---------------- phase 1: one tile per wave
    f32x4 Oq = {0.f, 0.f, 0.f, 0.f};
    if (role == 0) {
      f32x4 Pacc = {0.f, 0.f, 0.f, 0.f};
      #pragma unroll
      for (int kk = 0; kk < 8; ++kk) {
        f16x8 ka = *(const f16x8*)&Kh[(16 * tm + lr) * LDK + 32 * kk + 8 * lq];
        f16x8 sb = *(const f16x8*)&Sh[(16 * tn + lr) * LDK + 32 * kk + 8 * lq];
        Pacc = __builtin_amdgcn_mfma_f32_16x16x32_f16(ka, sb, Pacc, 0, 0, 0);
      }
      const int i = 16 * tn + lr;
      const int t0 = 16 * tm + 4 * lq;
      f16x4 u0;
      #pragma unroll
      for (int r = 0; r < 4; ++r) u0[r] = (f16)(Vl[(t0 + r) * LDV + i] - Pacc[r]);
      *(f16x4*)&U0T[i * LDT + t0] = u0;
    } else {
      #pragma unroll
      for (int kk = 0; kk < 8; ++kk) {
        f16x8 qa = *(const f16x8*)&Qh[(16 * tm + lr) * LDK + 32 * kk + 8 * lq];
        f16x8 sb = *(const f16x8*)&Sh[(16 * tn + lr) * LDK + 32 * kk + 8 * lq];
        Oq = __builtin_amdgcn_mfma_f32_16x16x32_f16(qa, sb, Oq, 0, 0, 0);
      }
    }
    __syncthreads();   // B1: U0T visible; Kh/Qh/Vl/Sh reads done

    // write-late: Kh/Qh/Vl for c+1 (no readers until phase 1 of c+1)
    if (more) {
      #pragma unroll
      for (int m = 0; m < 2; ++m) {
        *(f16x8*)&Kh[st_t * LDK + st_cg * 16 + 8 * m] = nk[m];
        *(f16x8*)&Qh[st_t * LDK + st_cg * 16 + 8 * m] = nq[m];
      }
      *(float2*)&Vl[st_t * LDV + st_c2] = make_float2((float)nv[0], (float)nv[1]);
    }
    // ---------------- phase 2: U = W @ U0 (P-waves)
    if (role == 0) {
      f16x8 wa = *(const f16x8*)&Wl[(16 * tm + lr) * LDT + 8 * lq];
      f16x8 ub = *(const f16x8*)&U0T[(16 * tn + lr) * LDT + 8 * lq];
      f32x4 z = {0.f, 0.f, 0.f, 0.f};
      f32x4 Ud = __builtin_amdgcn_mfma_f32_16x16x32_f16(wa, ub, z, 0, 0, 0);
      const int i = 16 * tn + lr;
      const int t0 = 16 * tm + 4 * lq;
      f16x4 uh;
      #pragma unroll
      for (int r = 0; r < 4; ++r) uh[r] = (f16)Ud[r];
      *(f16x4*)&UT[i * LDT + t0] = uh;
    }
    __syncthreads();   // B2: UT visible; Wl reads done

    // write-late: Wl for c+1
    if (more && tid < 160) ((f16x8*)Wl)[tid] = nwg;

    // ---------------- phase 3 (Oq-waves) concurrent with phase 4 (all)
    if (role == 1) {
      f16x8 ga = *(const f16x8*)&Gl[(16 * tm + lr) * LDT + 8 * lq];
      f16x8 ub = *(const f16x8*)&UT[(16 * tn + lr) * LDT + 8 * lq];
      f32x4 O = __builtin_amdgcn_mfma_f32_16x16x32_f16(ga, ub, Oq, 0, 0, 0);
      const int i = 16 * tn + lr;
      const int tt0 = 16 * tm + 4 * lq;
      #pragma unroll
      for (int r = 0; r < 4; ++r) {
        const float sq = O[r];
        const float sig = 1.0f / (1.0f + __expf(-sq));
        out[(size_t)(t0g + tt0 + r) * ST + b * N_DIM + i0 + i] = sq * sq * sig;
      }
    }
    #pragma unroll
    for (int ti = 0; ti < 2; ++ti) {
      f16x8 ua = *(const f16x8*)&UT[(16 * ti + lr) * LDT + 8 * lq];
      #pragma unroll
      for (int jt = 0; jt < 2; ++jt) {
        f16x8 kb = *(const f16x8*)&KhT[(32 * w + 16 * jt + lr) * LDT + 8 * lq];
        acc[ti][jt] = __builtin_amdgcn_mfma_f32_16x16x32_f16(ua, kb, acc[ti][jt], 0, 0, 0);
      }
    }
    #pragma unroll
    for (int ti = 0; ti < 2; ++ti)
      #pragma unroll
      for (int jt = 0; jt < 2; ++jt)
        #pragma unroll
        for (int r = 0; r < 4; ++r)
          Sh[(16 * ti + 4 * lq + r) * LDK + 32 * w + 16 * jt + lr] = (f16)acc[ti][jt][r];
    __syncthreads();   // B3: Gl/KhT/UT reads + Sh refresh done

    // write-late: Gl/KhT for c+1 (readers at phases 3/4 of c+1, >=2 barriers away)
    if (more) {
      #pragma unroll
      for (int m = 0; m < 2; ++m)
        *(f16x8*)&KhT[kt_row * LDT + 8 * (kt_m0 + m)] = nkt[m];
      if (tid >= 160 && tid < 320) ((f16x8*)Gl)[tid - 160] = nwg;
    }
  }
}

// ---------------------------------------------------------------------------
extern "C" void kernel_launch(void* const* d_in, const int* in_sizes, int n_in,
                              void* d_out, int out_size, void* d_ws, size_t ws_size,
                              hipStream_t stream) {
  (void)in_sizes; (void)n_in; (void)out_size; (void)ws_size;
  const float* x  = (const float*)d_in[0];
  const float* S0 = (const float*)d_in[1];
  const float* Wk = (const float*)d_in[2];
  const float* Wv = (const float*)d_in[3];
  const float* Wq = (const float*)d_in[4];
  float* outp = (float*)d_out;

  // ws: kn | v | q (f16, 3 x 8.4MB) | Wg | Gg | KTg (8.4MB) | Wh  ~= 37.8MB
  f16* kn  = (f16*)d_ws;
  f16* vv  = kn + (size_t)M_DIM * N_DIM;
  f16* qq  = vv + (size_t)M_DIM * N_DIM;
  f16* Wg  = qq + (size_t)M_DIM * N_DIM;
  f16* Gg  = Wg + (size_t)B_DIM * NCHUNK * 1280;
  f16* KTg = Gg + (size_t)B_DIM * NCHUNK * 1280;
  f16* Wh  = KTg + (size_t)B_DIM * NCHUNK * N_DIM * CHUNK;

  dim3 gw(N_DIM * D_DIM / 8 / 256, 3);
  cvt_w_kernel<<<gw, 256, 0, stream>>>(Wk, Wv, Wq, Wh);
  dim3 gg(M_DIM / 128, 6);
  proj_gemm_mfma<<<gg, 256, 0, stream>>>(x, Wh, kn, vv, qq);
  knorm_kernel<<<M_DIM / 4, 256, 0, stream>>>(kn);
  precompute_wg<<<B_DIM * NCHUNK, 256, 0, stream>>>(kn, qq, Wg, Gg, KTg);
  scan_chunked<<<B_DIM * (N_DIM / IBLK), 512, 0, stream>>>(kn, vv, qq, S0, Wg, Gg, KTg, outp);
}